// Round 20
// baseline (187.758 us; speedup 1.0000x reference)
//
#include <hip/hip_runtime.h>

#define DEV __device__ __forceinline__

typedef __attribute__((ext_vector_type(4))) float f32x4;
typedef __attribute__((ext_vector_type(8))) short bf16x8;
typedef __attribute__((ext_vector_type(4))) short bf16x4;
typedef __attribute__((ext_vector_type(4))) unsigned int u32x4;
typedef __attribute__((ext_vector_type(2))) unsigned int u32x2;

DEV short f2bf(float f) {
  union { float f; unsigned u; } c; c.f = f;
  unsigned r = c.u + 0x7FFFu + ((c.u >> 16) & 1u);  // RNE
  return (short)(r >> 16);
}

DEV unsigned cvtpk(float lo, float hi) {  // 2 f32 -> packed 2x bf16 (RNE)
  unsigned r;
  asm("v_cvt_pk_bf16_f32 %0, %1, %2" : "=v"(r) : "v"(lo), "v"(hi));
  return r;
}

DEV float exp2r(float x) { return __builtin_amdgcn_exp2f(x); }

DEV void gl_lds16(short* lds, const short* g) {
  __builtin_amdgcn_global_load_lds(
      (__attribute__((address_space(1))) void*)(void*)g,
      (__attribute__((address_space(3))) void*)lds, 16, 0, 0);
}

DEV int xcd_swz(int orig, int nwg) {
  int q = nwg >> 3, r = nwg & 7;
  int xcd = orig & 7, idx = orig >> 3;
  return (xcd < r ? xcd * (q + 1) : r * (q + 1) + (xcd - r) * q) + idx;
}

// ---------------- elementwise fp32 -> bf16 (x4) : Wo only now ----------------
__global__ __launch_bounds__(256) void k_cvt(const float* __restrict__ in, short* __restrict__ out) {
  int i = blockIdx.x * 256 + threadIdx.x;
  float4 v = reinterpret_cast<const float4*>(in)[i];
  bf16x4 o;
  o[0] = f2bf(v.x); o[1] = f2bf(v.y); o[2] = f2bf(v.z); o[3] = f2bf(v.w);
  reinterpret_cast<bf16x4*>(out)[i] = o;
}

// ---------------- transpose + cvt ----------------
__global__ __launch_bounds__(256) void k_tcvt(const float* __restrict__ W, short* __restrict__ WT,
                                              int Kd, int Nd) {
  __shared__ float t[32][33];
  int nb = blockIdx.x * 32, kb = blockIdx.y * 32;
  int tx = threadIdx.x, ty = threadIdx.y;
#pragma unroll
  for (int i = ty; i < 32; i += 8) t[i][tx] = W[(long)(kb + i) * Nd + nb + tx];
  __syncthreads();
#pragma unroll
  for (int i = ty; i < 32; i += 8) WT[(long)(nb + i) * Kd + kb + tx] = f2bf(t[tx][i]);
}

// ---------------- fused bias ----------------
__global__ __launch_bounds__(256) void k_bias(const float* __restrict__ bo, const float* __restrict__ bp,
                                              const float* __restrict__ Wp, float* __restrict__ bc) {
  int j = blockIdx.x * 256 + threadIdx.x;
  int k0 = blockIdx.y * 48;
  float s = 0.f;
#pragma unroll
  for (int k = 0; k < 48; ++k) s += bo[k0 + k] * Wp[(long)(k0 + k) * 768 + j];
  if (blockIdx.y == 0) s += bp[j];
  atomicAdd(&bc[j], s);
}

// ======== GEMM1: fused fp32-A (reg-staged cvt) x bf16-B^T, scatter epilogue ========
// A staged: float4 global loads -> cvtpk -> swizzled ds_write_b64 (T14 issue-early/write-late).
// B staged: global_load_lds (2-slot). One __syncthreads per iter.
__global__ __launch_bounds__(256) void k_gemmA(
    const float* __restrict__ X, const short* __restrict__ BT, const float* __restrict__ bias,
    short* __restrict__ Qp, short* __restrict__ Kp, short* __restrict__ VT, int K) {
  __shared__ short As[2][128 * 32];
  __shared__ short Bs[2][128 * 32];
  const int tid = threadIdx.x;
  const int w = tid >> 6, lane = tid & 63;
  const int lr = lane & 15, g = lane >> 4;

  const int nbx = gridDim.x;
  int lin = blockIdx.y * nbx + blockIdx.x;
  lin = xcd_swz(lin, nbx * gridDim.y);
  const int bx = lin % nbx, by = lin / nbx;
  const int m0 = by * 128, n0 = bx * 128;
  const int wm = (w >> 1) * 64, wn = (w & 1) * 64;

  f32x4 acc[4][4];
#pragma unroll
  for (int i = 0; i < 4; ++i)
#pragma unroll
    for (int j = 0; j < 4; ++j)
#pragma unroll
      for (int r = 0; r < 4; ++r) acc[i][j][r] = 0.f;

  const float* Xb = X + (long)m0 * K;
  const short* Bb = BT + (long)n0 * K;
  const int nk = K >> 5;  // 24

  // A reg-staging geometry: lane covers row=arow+j*32, k-granule gi=tid&7 (4 floats)
  const int arow = tid >> 3;        // 0..31
  const int gi = tid & 7;           // granule 0..7 (4 floats each)
  // B gl_lds geometry (proven): row=tid>>2 (+64), swizzled 16B chunk
  const int brow = tid >> 2;
  const int bcs = tid & 3;

  float4 avreg[4];
  auto LOAD_A = [&](int kt) {
#pragma unroll
    for (int j = 0; j < 4; ++j)
      avreg[j] = *reinterpret_cast<const float4*>(Xb + (long)(arow + j * 32) * K + (kt << 5) + gi * 4);
  };
  auto WRITE_A = [&](int s) {
#pragma unroll
    for (int j = 0; j < 4; ++j) {
      int row = arow + j * 32;
      int sc = (gi >> 1) ^ ((row >> 1) & 3);          // swizzled 16B chunk
      int goff = (sc * 2 + (gi & 1)) * 4;             // short offset of 8B granule
      u32x2 pk;
      pk[0] = cvtpk(avreg[j].x, avreg[j].y);
      pk[1] = cvtpk(avreg[j].z, avreg[j].w);
      *reinterpret_cast<u32x2*>(&As[s][row * 32 + goff]) = pk;
    }
  };
  auto STAGE_B = [&](int s, int kt) {
    const int k0 = kt << 5;
#pragma unroll
    for (int i = 0; i < 2; ++i) {
      int row = brow + i * 64;
      int cs = bcs ^ ((row >> 1) & 3);
      gl_lds16(&Bs[s][(i * 256 + w * 64) * 8], Bb + (long)row * K + k0 + cs * 8);
    }
  };

  // prologue: tile 0
  LOAD_A(0);
  STAGE_B(0, 0);
  asm volatile("s_waitcnt vmcnt(0)" ::: "memory");
  WRITE_A(0);
  __syncthreads();

  for (int kt = 0; kt < nk; ++kt) {
    const int cur = kt & 1;
    if (kt + 1 < nk) {
      LOAD_A(kt + 1);          // issue early: latency hides under compute
      STAGE_B(cur ^ 1, kt + 1);
    }

    const short* AsC = As[cur];
    const short* BsC = Bs[cur];
    bf16x8 af[4], bf[4];
#pragma unroll
    for (int mi = 0; mi < 4; ++mi) {
      int r = wm + mi * 16 + lr;
      int c = g ^ ((r >> 1) & 3);
      af[mi] = *reinterpret_cast<const bf16x8*>(AsC + r * 32 + c * 8);
    }
#pragma unroll
    for (int nj = 0; nj < 4; ++nj) {
      int r = wn + nj * 16 + lr;
      int c = g ^ ((r >> 1) & 3);
      bf[nj] = *reinterpret_cast<const bf16x8*>(BsC + r * 32 + c * 8);
    }
    __builtin_amdgcn_s_setprio(1);
#pragma unroll
    for (int mi = 0; mi < 4; ++mi)
#pragma unroll
      for (int nj = 0; nj < 4; ++nj)
        acc[mi][nj] = __builtin_amdgcn_mfma_f32_16x16x32_bf16(af[mi], bf[nj], acc[mi][nj], 0, 0, 0);
    __builtin_amdgcn_s_setprio(0);

    if (kt + 1 < nk) {
      asm volatile("s_waitcnt vmcnt(0)" ::: "memory");  // A regs + B LDS landed
      WRITE_A(cur ^ 1);
    }
    __syncthreads();
  }

  // scatter epilogue (proven MODE-0 mapping)
#pragma unroll
  for (int nj = 0; nj < 4; ++nj) {
    int col = n0 + wn + nj * 16 + lr;
    float bv = bias[col];
    int h = col / 144;
    int rem = col - h * 144;
    int s = rem / 48;
    int d = rem - s * 48;
#pragma unroll
    for (int mi = 0; mi < 4; ++mi)
#pragma unroll
      for (int r = 0; r < 4; ++r) {
        int row = m0 + wm + mi * 16 + g * 4 + r;
        float val = acc[mi][nj][r] + bv;
        int b = row >> 11, n = row & 2047;
        int bh = (b << 4) + h;
        if (s == 0) {
          long o = ((long)(bh * 2048 + n)) * 64 + d;
          Qp[o] = f2bf(val * 0.20823051649867783f);  // log2(e)/sqrt(48)
          if (d < 16) Qp[o + 48] = 0;
        } else if (s == 1) {
          long o = ((long)(bh * 2048 + n)) * 64 + d;
          Kp[o] = f2bf(val);
          if (d < 16) Kp[o + 48] = 0;
        } else {
          VT[((long)(bh * 48 + d)) * 2048 + n] = f2bf(val);
        }
      }
  }
}

// ---------------- GEMM (R11 proven): 128x128, 3-buf counted-vmcnt ----------------
// MODE 2: fp32 out + bias ; MODE 3: bf16 out no bias
template <int MODE>
__global__ __launch_bounds__(256) void k_gemm(
    const short* __restrict__ A, const short* __restrict__ BT, const float* __restrict__ bias,
    short* __restrict__ Cb, float* __restrict__ Cf, int M, int N, int K) {
  __shared__ short As[3][128 * 32];
  __shared__ short Bs[3][128 * 32];
  const int tid = threadIdx.x;
  const int w = tid >> 6, lane = tid & 63;
  const int lr = lane & 15, g = lane >> 4;

  const int nbx = gridDim.x;
  int lin = blockIdx.y * nbx + blockIdx.x;
  lin = xcd_swz(lin, nbx * gridDim.y);
  const int bx = lin % nbx, by = lin / nbx;
  const int m0 = by * 128, n0 = bx * 128;
  const int wm = (w >> 1) * 64, wn = (w & 1) * 64;

  f32x4 acc[4][4];
#pragma unroll
  for (int i = 0; i < 4; ++i)
#pragma unroll
    for (int j = 0; j < 4; ++j)
#pragma unroll
      for (int r = 0; r < 4; ++r) acc[i][j][r] = 0.f;

  const short* Ab = A + (long)m0 * K;
  const short* Bb = BT + (long)n0 * K;
  const int row_s = tid >> 2;
  const int c_s = tid & 3;
  const int nk = K >> 5;

  auto STAGE = [&](int b, int kt) {
    const int k0 = kt << 5;
#pragma unroll
    for (int i = 0; i < 2; ++i) {
      int row = row_s + i * 64;
      int cs = c_s ^ ((row >> 1) & 3);
      gl_lds16(&As[b][(i * 256 + w * 64) * 8], Ab + (long)row * K + k0 + cs * 8);
      gl_lds16(&Bs[b][(i * 256 + w * 64) * 8], Bb + (long)row * K + k0 + cs * 8);
    }
  };

  STAGE(0, 0);
  STAGE(1, 1);

  for (int kt = 0; kt < nk; ++kt) {
    if (kt < nk - 1) asm volatile("s_waitcnt vmcnt(4)" ::: "memory");
    else             asm volatile("s_waitcnt vmcnt(0)" ::: "memory");
    __builtin_amdgcn_s_barrier();

    if (kt + 2 < nk) STAGE((kt + 2) % 3, kt + 2);

    const short* AsC = As[kt % 3];
    const short* BsC = Bs[kt % 3];
    bf16x8 af[4], bf[4];
#pragma unroll
    for (int mi = 0; mi < 4; ++mi) {
      int r = wm + mi * 16 + lr;
      int c = g ^ ((r >> 1) & 3);
      af[mi] = *reinterpret_cast<const bf16x8*>(AsC + r * 32 + c * 8);
    }
#pragma unroll
    for (int nj = 0; nj < 4; ++nj) {
      int r = wn + nj * 16 + lr;
      int c = g ^ ((r >> 1) & 3);
      bf[nj] = *reinterpret_cast<const bf16x8*>(BsC + r * 32 + c * 8);
    }
    __builtin_amdgcn_s_setprio(1);
#pragma unroll
    for (int mi = 0; mi < 4; ++mi)
#pragma unroll
      for (int nj = 0; nj < 4; ++nj)
        acc[mi][nj] = __builtin_amdgcn_mfma_f32_16x16x32_bf16(af[mi], bf[nj], acc[mi][nj], 0, 0, 0);
    __builtin_amdgcn_s_setprio(0);
  }

#pragma unroll
  for (int nj = 0; nj < 4; ++nj) {
    int col = n0 + wn + nj * 16 + lr;
    float bv = (MODE == 3) ? 0.f : bias[col];
#pragma unroll
    for (int mi = 0; mi < 4; ++mi)
#pragma unroll
      for (int r = 0; r < 4; ++r) {
        int row = m0 + wm + mi * 16 + g * 4 + r;
        float val = acc[mi][nj][r] + bv;
        if (MODE == 2) Cf[(long)row * N + col] = val;
        else           Cb[(long)row * N + col] = f2bf(val);
      }
  }
}

// ---------------- flash attention v9 (R19): 8-wave, 256 q rows/block, 70.9 µs ----------------
__global__ __launch_bounds__(512, 4) void k_attn(const short* __restrict__ Q, const short* __restrict__ K,
                                                 const short* __restrict__ VT, short* __restrict__ AO) {
  const int tid = threadIdx.x, w = tid >> 6, lane = tid & 63;
  const int lr = lane & 15, g = lane >> 4;
  const int orig = blockIdx.x;
  const int logical = (orig & 7) * 64 + (orig >> 3);
  const int bh = logical >> 3;
  const int q0 = (logical & 7) * 256 + w * 32;

  const short* Qh = Q + (long)bh * 2048 * 64;
  const short* Kh = K + (long)bh * 2048 * 64;
  const short* VTh = VT + (long)bh * 48 * 2048;

  __shared__ short Ks[2][64 * 64];
  __shared__ short Vs[2][48 * 64];

  const int r_l = lane >> 3, c_l = lane & 7;
  const int gc8 = (c_l ^ r_l) * 8;

  bf16x8 bq0 = *reinterpret_cast<const bf16x8*>(Qh + (q0 + lr) * 64 + g * 8);
  bf16x8 bq1 = *reinterpret_cast<const bf16x8*>(Qh + (q0 + lr) * 64 + 32 + g * 8);
  bf16x8 bq2 = *reinterpret_cast<const bf16x8*>(Qh + (q0 + 16 + lr) * 64 + g * 8);
  bf16x8 bq3 = *reinterpret_cast<const bf16x8*>(Qh + (q0 + 16 + lr) * 64 + 32 + g * 8);

  bf16x8 vones;
#pragma unroll
  for (int i = 0; i < 8; ++i) vones[i] = (short)0x3F80;

  f32x4 accA[3], accB[3];
#pragma unroll
  for (int df = 0; df < 3; ++df)
#pragma unroll
    for (int r = 0; r < 4; ++r) { accA[df][r] = 0.f; accB[df][r] = 0.f; }
  f32x4 acclA = {0.f, 0.f, 0.f, 0.f}, acclB = {0.f, 0.f, 0.f, 0.f};

  const short* kg = Kh + (long)(w * 8 + r_l) * 64 + gc8;
  const short* vg = VTh + (long)(w * 8 + r_l) * 2048 + gc8;

  auto STAGE = [&](int b) {
    gl_lds16(&Ks[b][w * 512], kg);
    if (w < 6) gl_lds16(&Vs[b][w * 512], vg);
  };

  STAGE(0);
  kg += 4096; vg += 64;
  asm volatile("s_waitcnt vmcnt(0)" ::: "memory");
  __syncthreads();

  const int sw = lr & 7;
  const int goff = (g & 1) * 4;
  const int ghalf = g >> 1;

  for (int t = 0; t < 32; ++t) {
    const int cur = t & 1;
    if (t < 31) {
      STAGE(cur ^ 1);
      kg += 4096; vg += 64;
    }

    const short* KsC = Ks[cur];
    const short* VsC = Vs[cur];

    f32x4 stA[4], stB[4];
    __builtin_amdgcn_s_setprio(1);
#pragma unroll
    for (int kf = 0; kf < 4; ++kf) {
      const short* kr = KsC + (kf * 16 + lr) * 64;
      bf16x8 a0 = *reinterpret_cast<const bf16x8*>(kr + (g ^ sw) * 8);
      bf16x8 a1 = *reinterpret_cast<const bf16x8*>(kr + ((4 + g) ^ sw) * 8);
      f32x4 sA = {0.f, 0.f, 0.f, 0.f}, sB = {0.f, 0.f, 0.f, 0.f};
      sA = __builtin_amdgcn_mfma_f32_16x16x32_bf16(a0, bq0, sA, 0, 0, 0);
      sB = __builtin_amdgcn_mfma_f32_16x16x32_bf16(a0, bq2, sB, 0, 0, 0);
      sA = __builtin_amdgcn_mfma_f32_16x16x32_bf16(a1, bq1, sA, 0, 0, 0);
      sB = __builtin_amdgcn_mfma_f32_16x16x32_bf16(a1, bq3, sB, 0, 0, 0);
      stA[kf] = sA; stB[kf] = sB;
    }
    __builtin_amdgcn_s_setprio(0);

#pragma unroll
    for (int kf = 0; kf < 4; ++kf)
#pragma unroll
      for (int r = 0; r < 4; ++r) {
        stA[kf][r] = exp2r(stA[kf][r]);
        stB[kf][r] = exp2r(stB[kf][r]);
      }

    __builtin_amdgcn_s_setprio(1);
#pragma unroll
    for (int ks = 0; ks < 2; ++ks) {
      u32x4 bwA, bwB;
      bwA[0] = cvtpk(stA[2 * ks][0], stA[2 * ks][1]);
      bwA[1] = cvtpk(stA[2 * ks][2], stA[2 * ks][3]);
      bwA[2] = cvtpk(stA[2 * ks + 1][0], stA[2 * ks + 1][1]);
      bwA[3] = cvtpk(stA[2 * ks + 1][2], stA[2 * ks + 1][3]);
      bwB[0] = cvtpk(stB[2 * ks][0], stB[2 * ks][1]);
      bwB[1] = cvtpk(stB[2 * ks][2], stB[2 * ks][3]);
      bwB[2] = cvtpk(stB[2 * ks + 1][0], stB[2 * ks + 1][1]);
      bwB[3] = cvtpk(stB[2 * ks + 1][2], stB[2 * ks + 1][3]);
      bf16x8 bpA = __builtin_bit_cast(bf16x8, bwA);
      bf16x8 bpB = __builtin_bit_cast(bf16x8, bwB);
      const int off_lo = ((ks * 4 + ghalf) ^ sw) * 8 + goff;
      const int off_hi = ((ks * 4 + 2 + ghalf) ^ sw) * 8 + goff;
      acclA = __builtin_amdgcn_mfma_f32_16x16x32_bf16(vones, bpA, acclA, 0, 0, 0);
      acclB = __builtin_amdgcn_mfma_f32_16x16x32_bf16(vones, bpB, acclB, 0, 0, 0);
#pragma unroll
      for (int df = 0; df < 3; ++df) {
        const short* vbase = VsC + (df * 16 + lr) * 64;
        union { bf16x8 v; bf16x4 h[2]; } av;
        av.h[0] = *reinterpret_cast<const bf16x4*>(vbase + off_lo);
        av.h[1] = *reinterpret_cast<const bf16x4*>(vbase + off_hi);
        accA[df] = __builtin_amdgcn_mfma_f32_16x16x32_bf16(av.v, bpA, accA[df], 0, 0, 0);
        accB[df] = __builtin_amdgcn_mfma_f32_16x16x32_bf16(av.v, bpB, accB[df], 0, 0, 0);
      }
    }
    __builtin_amdgcn_s_setprio(0);

    asm volatile("s_waitcnt vmcnt(0)" ::: "memory");
    __syncthreads();
  }

  int b = bh >> 4, h = bh & 15;
  float invA = 1.f / acclA[0];
  float invB = 1.f / acclB[0];
  long rowA = ((long)((b << 11) + q0 + lr)) * 768 + h * 48;
  long rowB = ((long)((b << 11) + q0 + 16 + lr)) * 768 + h * 48;
#pragma unroll
  for (int df = 0; df < 3; ++df) {
    bf16x4 oA, oB;
#pragma unroll
    for (int r = 0; r < 4; ++r) { oA[r] = f2bf(accA[df][r] * invA); oB[r] = f2bf(accB[df][r] * invB); }
    *reinterpret_cast<bf16x4*>(AO + rowA + df * 16 + g * 4) = oA;
    *reinterpret_cast<bf16x4*>(AO + rowB + df * 16 + g * 4) = oB;
  }
}

extern "C" void kernel_launch(void* const* d_in, const int* in_sizes, int n_in,
                              void* d_out, int out_size, void* d_ws, size_t ws_size,
                              hipStream_t stream) {
  const float* x    = (const float*)d_in[0];
  const float* Wqkv = (const float*)d_in[1];
  const float* bqkv = (const float*)d_in[2];
  const float* Wo   = (const float*)d_in[3];
  const float* bo   = (const float*)d_in[4];
  const float* Wp   = (const float*)d_in[5];
  const float* bp   = (const float*)d_in[6];

  char* ws = (char*)d_ws;
  // live-range audited layout (xb region now fully scratch; no x conversion pass):
  short* WqkvT = (short*)(ws + 12582912);   // [tcvt .. gemm1)
  short* Wob   = (short*)(ws + 16121856);   // [cvt .. gemm3)
  short* WpT   = (short*)(ws + 17301504);   // [tcvt .. gemm3)
  short* Qp    = (short*)(ws + 18481152);   // [gemm1 .. attn)
  short* Kp    = (short*)(ws + 35258368);   // [gemm1 .. attn)
  short* VT    = (short*)(ws + 52035584);   // [gemm1 .. attn)
  short* AO    = (short*)(ws + 64618496);   // [attn .. gemm2)
  short* WoWpT = (short*)(ws + 2097152);    // [gemm3 .. gemm2) in scratch region
  float* bc    = (float*)(ws + 4194304);    // [k_bias .. gemm2) in scratch region

  k_tcvt<<<dim3(72, 24), dim3(32, 8), 0, stream>>>(Wqkv, WqkvT, 768, 2304);
  k_tcvt<<<dim3(24, 24), dim3(32, 8), 0, stream>>>(Wp, WpT, 768, 768);
  k_cvt<<<576, 256, 0, stream>>>(Wo, Wob);

  // GEMM1: fused fp32-A conversion + scatter (reads x directly)
  k_gemmA<<<dim3(18, 64), 256, 0, stream>>>(x, WqkvT, bqkv, Qp, Kp, VT, 768);

  k_gemm<3><<<dim3(6, 6), 256, 0, stream>>>(WpT, Wob, nullptr, WoWpT, nullptr, 768, 768, 768);
  hipMemsetAsync(bc, 0, 768 * sizeof(float), stream);
  k_bias<<<dim3(3, 16), 256, 0, stream>>>(bo, bp, Wp, bc);

  k_attn<<<512, 512, 0, stream>>>(Qp, Kp, VT, AO);
  k_gemm<2><<<dim3(6, 64), 256, 0, stream>>>(AO, WoWpT, bc, nullptr, (float*)d_out, 8192, 768, 768);
}

// Round 21
// 178.486 us; speedup vs baseline: 1.0519x; 1.0519x over previous
//
#include <hip/hip_runtime.h>

#define DEV __device__ __forceinline__

typedef __attribute__((ext_vector_type(4))) float f32x4;
typedef __attribute__((ext_vector_type(8))) short bf16x8;
typedef __attribute__((ext_vector_type(4))) short bf16x4;
typedef __attribute__((ext_vector_type(4))) unsigned int u32x4;

DEV short f2bf(float f) {
  union { float f; unsigned u; } c; c.f = f;
  unsigned r = c.u + 0x7FFFu + ((c.u >> 16) & 1u);  // RNE
  return (short)(r >> 16);
}

DEV unsigned cvtpk(float lo, float hi) {
  unsigned r;
  asm("v_cvt_pk_bf16_f32 %0, %1, %2" : "=v"(r) : "v"(lo), "v"(hi));
  return r;
}

DEV float exp2r(float x) { return __builtin_amdgcn_exp2f(x); }

DEV void gl_lds16(short* lds, const short* g) {
  __builtin_amdgcn_global_load_lds(
      (__attribute__((address_space(1))) void*)(void*)g,
      (__attribute__((address_space(3))) void*)lds, 16, 0, 0);
}

DEV int xcd_swz(int orig, int nwg) {
  int q = nwg >> 3, r = nwg & 7;
  int xcd = orig & 7, idx = orig >> 3;
  return (xcd < r ? xcd * (q + 1) : r * (q + 1) + (xcd - r) * q) + idx;
}

// ---------------- elementwise fp32 -> bf16 (x4), two tensors ----------------
__global__ __launch_bounds__(256) void k_cvt2(const float* __restrict__ in1, short* __restrict__ out1,
                                              int nb1, const float* __restrict__ in2, short* __restrict__ out2) {
  int b = blockIdx.x;
  const float* in = in1; short* out = out1;
  if (b >= nb1) { in = in2; out = out2; b -= nb1; }
  int i = b * 256 + threadIdx.x;
  float4 v = reinterpret_cast<const float4*>(in)[i];
  bf16x4 o;
  o[0] = f2bf(v.x); o[1] = f2bf(v.y); o[2] = f2bf(v.z); o[3] = f2bf(v.w);
  reinterpret_cast<bf16x4*>(out)[i] = o;
}

// ---------------- transpose + cvt ----------------
__global__ __launch_bounds__(256) void k_tcvt(const float* __restrict__ W, short* __restrict__ WT,
                                              int Kd, int Nd) {
  __shared__ float t[32][33];
  int nb = blockIdx.x * 32, kb = blockIdx.y * 32;
  int tx = threadIdx.x, ty = threadIdx.y;
#pragma unroll
  for (int i = ty; i < 32; i += 8) t[i][tx] = W[(long)(kb + i) * Nd + nb + tx];
  __syncthreads();
#pragma unroll
  for (int i = ty; i < 32; i += 8) WT[(long)(nb + i) * Kd + kb + tx] = f2bf(t[tx][i]);
}

// ---------------- fused bias ----------------
__global__ __launch_bounds__(256) void k_bias(const float* __restrict__ bo, const float* __restrict__ bp,
                                              const float* __restrict__ Wp, float* __restrict__ bc) {
  int j = blockIdx.x * 256 + threadIdx.x;
  int k0 = blockIdx.y * 48;
  float s = 0.f;
#pragma unroll
  for (int k = 0; k < 48; ++k) s += bo[k0 + k] * Wp[(long)(k0 + k) * 768 + j];
  if (blockIdx.y == 0) s += bp[j];
  atomicAdd(&bc[j], s);
}

// ---------------- GEMM (R11 proven): 128x128, 3-buf counted-vmcnt ----------------
// MODE 0: scatter -> Qp/Kp (padded 64), VT ; MODE 2: fp32 out + bias ; MODE 3: bf16 out no bias
template <int MODE>
__global__ __launch_bounds__(256) void k_gemm(
    const short* __restrict__ A, const short* __restrict__ BT, const float* __restrict__ bias,
    short* __restrict__ Cb, float* __restrict__ Cf,
    short* __restrict__ Qp, short* __restrict__ Kp, short* __restrict__ VT,
    int M, int N, int K) {
  __shared__ short As[3][128 * 32];
  __shared__ short Bs[3][128 * 32];
  const int tid = threadIdx.x;
  const int w = tid >> 6, lane = tid & 63;
  const int lr = lane & 15, g = lane >> 4;

  const int nbx = gridDim.x;
  int lin = blockIdx.y * nbx + blockIdx.x;
  lin = xcd_swz(lin, nbx * gridDim.y);
  const int bx = lin % nbx, by = lin / nbx;
  const int m0 = by * 128, n0 = bx * 128;
  const int wm = (w >> 1) * 64, wn = (w & 1) * 64;

  f32x4 acc[4][4];
#pragma unroll
  for (int i = 0; i < 4; ++i)
#pragma unroll
    for (int j = 0; j < 4; ++j)
#pragma unroll
      for (int r = 0; r < 4; ++r) acc[i][j][r] = 0.f;

  const short* Ab = A + (long)m0 * K;
  const short* Bb = BT + (long)n0 * K;
  const int row_s = tid >> 2;
  const int c_s = tid & 3;
  const int nk = K >> 5;

  auto STAGE = [&](int b, int kt) {
    const int k0 = kt << 5;
#pragma unroll
    for (int i = 0; i < 2; ++i) {
      int row = row_s + i * 64;
      int cs = c_s ^ ((row >> 1) & 3);
      gl_lds16(&As[b][(i * 256 + w * 64) * 8], Ab + (long)row * K + k0 + cs * 8);
      gl_lds16(&Bs[b][(i * 256 + w * 64) * 8], Bb + (long)row * K + k0 + cs * 8);
    }
  };

  STAGE(0, 0);
  STAGE(1, 1);

  for (int kt = 0; kt < nk; ++kt) {
    if (kt < nk - 1) asm volatile("s_waitcnt vmcnt(4)" ::: "memory");
    else             asm volatile("s_waitcnt vmcnt(0)" ::: "memory");
    __builtin_amdgcn_s_barrier();

    if (kt + 2 < nk) STAGE((kt + 2) % 3, kt + 2);

    const short* AsC = As[kt % 3];
    const short* BsC = Bs[kt % 3];
    bf16x8 af[4], bf[4];
#pragma unroll
    for (int mi = 0; mi < 4; ++mi) {
      int r = wm + mi * 16 + lr;
      int c = g ^ ((r >> 1) & 3);
      af[mi] = *reinterpret_cast<const bf16x8*>(AsC + r * 32 + c * 8);
    }
#pragma unroll
    for (int nj = 0; nj < 4; ++nj) {
      int r = wn + nj * 16 + lr;
      int c = g ^ ((r >> 1) & 3);
      bf[nj] = *reinterpret_cast<const bf16x8*>(BsC + r * 32 + c * 8);
    }
    __builtin_amdgcn_s_setprio(1);
#pragma unroll
    for (int mi = 0; mi < 4; ++mi)
#pragma unroll
      for (int nj = 0; nj < 4; ++nj)
        acc[mi][nj] = __builtin_amdgcn_mfma_f32_16x16x32_bf16(af[mi], bf[nj], acc[mi][nj], 0, 0, 0);
    __builtin_amdgcn_s_setprio(0);
  }

#pragma unroll
  for (int nj = 0; nj < 4; ++nj) {
    int col = n0 + wn + nj * 16 + lr;
    float bv = (MODE == 3) ? 0.f : bias[col];
    if (MODE == 0) {
      int h = col / 144;
      int rem = col - h * 144;
      int s = rem / 48;
      int d = rem - s * 48;
#pragma unroll
      for (int mi = 0; mi < 4; ++mi)
#pragma unroll
        for (int r = 0; r < 4; ++r) {
          int row = m0 + wm + mi * 16 + g * 4 + r;
          float val = acc[mi][nj][r] + bv;
          int b = row >> 11, n = row & 2047;
          int bh = (b << 4) + h;
          if (s == 0) {
            long o = ((long)(bh * 2048 + n)) * 64 + d;
            Qp[o] = f2bf(val * 0.20823051649867783f);  // log2(e)/sqrt(48)
            if (d < 16) Qp[o + 48] = 0;
          } else if (s == 1) {
            long o = ((long)(bh * 2048 + n)) * 64 + d;
            Kp[o] = f2bf(val);
            if (d < 16) Kp[o + 48] = 0;
          } else {
            VT[((long)(bh * 48 + d)) * 2048 + n] = f2bf(val);
          }
        }
    } else {
#pragma unroll
      for (int mi = 0; mi < 4; ++mi)
#pragma unroll
        for (int r = 0; r < 4; ++r) {
          int row = m0 + wm + mi * 16 + g * 4 + r;
          float val = acc[mi][nj][r] + bv;
          if (MODE == 2) Cf[(long)row * N + col] = val;
          else           Cb[(long)row * N + col] = f2bf(val);
        }
    }
  }
}

// ---------------- flash attention v9: 8-wave blocks, 256 q rows/block ----------------
__global__ __launch_bounds__(512, 4) void k_attn(const short* __restrict__ Q, const short* __restrict__ K,
                                                 const short* __restrict__ VT, short* __restrict__ AO) {
  const int tid = threadIdx.x, w = tid >> 6, lane = tid & 63;
  const int lr = lane & 15, g = lane >> 4;
  const int orig = blockIdx.x;
  const int logical = (orig & 7) * 64 + (orig >> 3);
  const int bh = logical >> 3;
  const int q0 = (logical & 7) * 256 + w * 32;

  const short* Qh = Q + (long)bh * 2048 * 64;
  const short* Kh = K + (long)bh * 2048 * 64;
  const short* VTh = VT + (long)bh * 48 * 2048;

  __shared__ short Ks[2][64 * 64];
  __shared__ short Vs[2][48 * 64];

  const int r_l = lane >> 3, c_l = lane & 7;
  const int gc8 = (c_l ^ r_l) * 8;

  bf16x8 bq0 = *reinterpret_cast<const bf16x8*>(Qh + (q0 + lr) * 64 + g * 8);
  bf16x8 bq1 = *reinterpret_cast<const bf16x8*>(Qh + (q0 + lr) * 64 + 32 + g * 8);
  bf16x8 bq2 = *reinterpret_cast<const bf16x8*>(Qh + (q0 + 16 + lr) * 64 + g * 8);
  bf16x8 bq3 = *reinterpret_cast<const bf16x8*>(Qh + (q0 + 16 + lr) * 64 + 32 + g * 8);

  bf16x8 vones;
#pragma unroll
  for (int i = 0; i < 8; ++i) vones[i] = (short)0x3F80;

  f32x4 accA[3], accB[3];
#pragma unroll
  for (int df = 0; df < 3; ++df)
#pragma unroll
    for (int r = 0; r < 4; ++r) { accA[df][r] = 0.f; accB[df][r] = 0.f; }
  f32x4 acclA = {0.f, 0.f, 0.f, 0.f}, acclB = {0.f, 0.f, 0.f, 0.f};

  const short* kg = Kh + (long)(w * 8 + r_l) * 64 + gc8;
  const short* vg = VTh + (long)(w * 8 + r_l) * 2048 + gc8;

  auto STAGE = [&](int b) {
    gl_lds16(&Ks[b][w * 512], kg);
    if (w < 6) gl_lds16(&Vs[b][w * 512], vg);
  };

  STAGE(0);
  kg += 4096; vg += 64;
  asm volatile("s_waitcnt vmcnt(0)" ::: "memory");
  __syncthreads();

  const int sw = lr & 7;
  const int goff = (g & 1) * 4;
  const int ghalf = g >> 1;

  for (int t = 0; t < 32; ++t) {
    const int cur = t & 1;
    if (t < 31) {
      STAGE(cur ^ 1);
      kg += 4096; vg += 64;
    }

    const short* KsC = Ks[cur];
    const short* VsC = Vs[cur];

    f32x4 stA[4], stB[4];
    __builtin_amdgcn_s_setprio(1);
#pragma unroll
    for (int kf = 0; kf < 4; ++kf) {
      const short* kr = KsC + (kf * 16 + lr) * 64;
      bf16x8 a0 = *reinterpret_cast<const bf16x8*>(kr + (g ^ sw) * 8);
      bf16x8 a1 = *reinterpret_cast<const bf16x8*>(kr + ((4 + g) ^ sw) * 8);
      f32x4 sA = {0.f, 0.f, 0.f, 0.f}, sB = {0.f, 0.f, 0.f, 0.f};
      sA = __builtin_amdgcn_mfma_f32_16x16x32_bf16(a0, bq0, sA, 0, 0, 0);
      sB = __builtin_amdgcn_mfma_f32_16x16x32_bf16(a0, bq2, sB, 0, 0, 0);
      sA = __builtin_amdgcn_mfma_f32_16x16x32_bf16(a1, bq1, sA, 0, 0, 0);
      sB = __builtin_amdgcn_mfma_f32_16x16x32_bf16(a1, bq3, sB, 0, 0, 0);
      stA[kf] = sA; stB[kf] = sB;
    }
    __builtin_amdgcn_s_setprio(0);

#pragma unroll
    for (int kf = 0; kf < 4; ++kf)
#pragma unroll
      for (int r = 0; r < 4; ++r) {
        stA[kf][r] = exp2r(stA[kf][r]);
        stB[kf][r] = exp2r(stB[kf][r]);
      }

    __builtin_amdgcn_s_setprio(1);
#pragma unroll
    for (int ks = 0; ks < 2; ++ks) {
      u32x4 bwA, bwB;
      bwA[0] = cvtpk(stA[2 * ks][0], stA[2 * ks][1]);
      bwA[1] = cvtpk(stA[2 * ks][2], stA[2 * ks][3]);
      bwA[2] = cvtpk(stA[2 * ks + 1][0], stA[2 * ks + 1][1]);
      bwA[3] = cvtpk(stA[2 * ks + 1][2], stA[2 * ks + 1][3]);
      bwB[0] = cvtpk(stB[2 * ks][0], stB[2 * ks][1]);
      bwB[1] = cvtpk(stB[2 * ks][2], stB[2 * ks][3]);
      bwB[2] = cvtpk(stB[2 * ks + 1][0], stB[2 * ks + 1][1]);
      bwB[3] = cvtpk(stB[2 * ks + 1][2], stB[2 * ks + 1][3]);
      bf16x8 bpA = __builtin_bit_cast(bf16x8, bwA);
      bf16x8 bpB = __builtin_bit_cast(bf16x8, bwB);
      const int off_lo = ((ks * 4 + ghalf) ^ sw) * 8 + goff;
      const int off_hi = ((ks * 4 + 2 + ghalf) ^ sw) * 8 + goff;
      acclA = __builtin_amdgcn_mfma_f32_16x16x32_bf16(vones, bpA, acclA, 0, 0, 0);
      acclB = __builtin_amdgcn_mfma_f32_16x16x32_bf16(vones, bpB, acclB, 0, 0, 0);
#pragma unroll
      for (int df = 0; df < 3; ++df) {
        const short* vbase = VsC + (df * 16 + lr) * 64;
        union { bf16x8 v; bf16x4 h[2]; } av;
        av.h[0] = *reinterpret_cast<const bf16x4*>(vbase + off_lo);
        av.h[1] = *reinterpret_cast<const bf16x4*>(vbase + off_hi);
        accA[df] = __builtin_amdgcn_mfma_f32_16x16x32_bf16(av.v, bpA, accA[df], 0, 0, 0);
        accB[df] = __builtin_amdgcn_mfma_f32_16x16x32_bf16(av.v, bpB, accB[df], 0, 0, 0);
      }
    }
    __builtin_amdgcn_s_setprio(0);

    asm volatile("s_waitcnt vmcnt(0)" ::: "memory");
    __syncthreads();
  }

  int b = bh >> 4, h = bh & 15;
  float invA = 1.f / acclA[0];
  float invB = 1.f / acclB[0];
  long rowA = ((long)((b << 11) + q0 + lr)) * 768 + h * 48;
  long rowB = ((long)((b << 11) + q0 + 16 + lr)) * 768 + h * 48;
#pragma unroll
  for (int df = 0; df < 3; ++df) {
    bf16x4 oA, oB;
#pragma unroll
    for (int r = 0; r < 4; ++r) { oA[r] = f2bf(accA[df][r] * invA); oB[r] = f2bf(accB[df][r] * invB); }
    *reinterpret_cast<bf16x4*>(AO + rowA + df * 16 + g * 4) = oA;
    *reinterpret_cast<bf16x4*>(AO + rowB + df * 16 + g * 4) = oB;
  }
}

extern "C" void kernel_launch(void* const* d_in, const int* in_sizes, int n_in,
                              void* d_out, int out_size, void* d_ws, size_t ws_size,
                              hipStream_t stream) {
  const float* x    = (const float*)d_in[0];
  const float* Wqkv = (const float*)d_in[1];
  const float* bqkv = (const float*)d_in[2];
  const float* Wo   = (const float*)d_in[3];
  const float* bo   = (const float*)d_in[4];
  const float* Wp   = (const float*)d_in[5];
  const float* bp   = (const float*)d_in[6];

  char* ws = (char*)d_ws;
  // live-range audited layout (R13-verified):
  short* xb    = (short*)(ws + 0);          // [cvt2 .. gemm1)
  short* WqkvT = (short*)(ws + 12582912);   // [tcvt .. gemm1)
  short* Wob   = (short*)(ws + 16121856);   // [cvt2 .. gemm3)
  short* WpT   = (short*)(ws + 17301504);   // [tcvt .. gemm3)
  short* Qp    = (short*)(ws + 18481152);   // [gemm1 .. attn)
  short* Kp    = (short*)(ws + 35258368);   // [gemm1 .. attn)
  short* VT    = (short*)(ws + 52035584);   // [gemm1 .. attn)
  short* AO    = (short*)(ws + 64618496);   // [attn .. gemm2)
  short* WoWpT = (short*)(ws + 2097152);    // [gemm3 .. gemm2) inside dead xb
  float* bc    = (float*)(ws + 4194304);    // [k_bias .. gemm2) inside dead xb (written AFTER gemm1)

  k_cvt2<<<6720, 256, 0, stream>>>(x, xb, 6144, Wo, Wob);
  k_tcvt<<<dim3(72, 24), dim3(32, 8), 0, stream>>>(Wqkv, WqkvT, 768, 2304);
  k_tcvt<<<dim3(24, 24), dim3(32, 8), 0, stream>>>(Wp, WpT, 768, 768);

  // GEMM1 (R11 proven 128^2 config)
  k_gemm<0><<<dim3(18, 64), 256, 0, stream>>>(xb, WqkvT, bqkv, nullptr, nullptr,
                                              Qp, Kp, VT, 8192, 2304, 768);
  k_gemm<3><<<dim3(6, 6), 256, 0, stream>>>(WpT, Wob, nullptr, WoWpT, nullptr,
                                            nullptr, nullptr, nullptr, 768, 768, 768);
  hipMemsetAsync(bc, 0, 768 * sizeof(float), stream);
  k_bias<<<dim3(3, 16), 256, 0, stream>>>(bo, bp, Wp, bc);

  // attention v9: 512 blocks x 512 threads (256 q rows/block)
  k_attn<<<512, 512, 0, stream>>>(Qp, Kp, VT, AO);
  k_gemm<2><<<dim3(6, 64), 256, 0, stream>>>(AO, WoWpT, bc, nullptr, (float*)d_out,
                                             nullptr, nullptr, nullptr, 8192, 768, 768);
}